// Round 11
// baseline (219.019 us; speedup 1.0000x reference)
//
#include <hip/hip_runtime.h>
#include <hip/hip_fp16.h>

// GraphConvolutionSparse forward. Coarse 128-row-bin sort + consumers that
// fine-sort each bin into LDS (128-key count/scan/rank) and register-
// accumulate rows (half2-per-lane gathers, unroll 4).
//
// Round-22: Wh table in LDS for consumer_xw. r10 (scatter_a||xw overlap)
// regressed 201->213 (split launches + 53KB-LDS xw blocks) -> reverted to
// r8 pipeline. Inference from top-5 structure: all non-adj kernels < 65.4
// us; budget 201.3 = adj 65.7 + prep ~3 + scatter ~25 + gaps ~10 leaves
// consumer_xw ~= 55-65 us (just under adj, invisible). Mechanism: same
// per-CU line-throughput wall as adj (800K gathers x 4 lines, L2-latency-
// bound, mean-8 rows). Fix: Wh = 131 KB FITS IN LDS. Persistent xw: 256
// blocks (1/CU @ 144 KB LDS), stage Wh once (coalesced int4, ~2 us
// aggregate), loop ~3 bins/block; per-edge Wh reads become ~6-cyc
// conflict-free ds_read (c*64+lane -> 2 lanes/bank = free) instead of
// ~200-cyc L2 gathers. Sort passes bit-identical to r8. Scatter (LDS-
// sorted coalesced stores), prep, consumer_adj = exact r8 (201.3 proven;
// adj 65.7, 9th confirmation, frozen).
// LDS atomics are INT only (native ds_add) — never float (round-7 lesson).

#define DOUT 128
#define RBB 128           // rows per bin
#define RBB_BITS 7
#define NKEY 128          // consumer fine-sort keys = row-in-bin
#define NBIN 1024         // max bins (N <= 131072 / 128)
#define NBMAX 4096        // mid-path hist table size (legacy, >= NBIN)
#define COLMASK 131071    // low 17 bits
#define CTH 512           // consumer threads (8 waves)
#define NW 8              // waves per consumer block
#define CAPX 1536         // stage slots per bin, X (mean 1023, +16 sigma)
#define CAPA 3072         // stage slots per bin, A (mean 2046, +22 sigma)
#define SCB 4096          // scatter elements per block (8/thread)
#define WHL4MAX 8192      // max int4 of Wh in LDS (D_IN <= 512: 512*16)

static inline size_t align_up(size_t x, size_t a) { return (x + a - 1) & ~(a - 1); }

__device__ inline int2 nt_load_int2(const int2* p) {
    long long v = __builtin_nontemporal_load((const long long*)p);
    int2 r; r.x = (int)(unsigned int)(v & 0xffffffffLL); r.y = (int)(v >> 32);
    return r;
}
__device__ inline void nt_store_float2(float2* p, float2 v) {
    union { float2 f; long long l; } u; u.f = v;
    __builtin_nontemporal_store(u.l, (long long*)p);
}

__device__ inline int wave_incl_scan(int v, int lane) {
    #pragma unroll
    for (int off = 1; off < 64; off <<= 1) {
        int up = __shfl_up(v, off, 64);
        if (lane >= off) v += up;
    }
    return v;
}

// ---- prep: zero bin counters + build Wh pair table ----
// Wh[c*64+l] = half2(W[c][2l], W[c][2l+1])  (row = 64 half2 = 256 B)
__global__ __launch_bounds__(256) void prep_kernel(int* __restrict__ cnts, int ncnt,
                                                   const float* __restrict__ W,
                                                   __half2* __restrict__ Wh, int whtot) {
    int i = blockIdx.x * 256 + threadIdx.x;
    if (i < ncnt) cnts[i] = 0;
    if (i < whtot) {
        int c = i >> 6, l = i & 63;
        Wh[i] = __floats2half2_rn(W[(c << 7) + 2 * l], W[(c << 7) + 2 * l + 1]);
    }
}

// ---- coarse histogram (mid path only) ----
__global__ __launch_bounds__(256) void hist_coarse(const int* __restrict__ xr, int nx,
                                                   const int* __restrict__ ar, int na,
                                                   int* __restrict__ cx, int* __restrict__ ca) {
    __shared__ int h[2 * NBMAX];
    for (int i = threadIdx.x; i < 2 * NBMAX; i += 256) h[i] = 0;
    __syncthreads();
    int base = blockIdx.x * 4096;
    int tot = nx + na;
    #pragma unroll
    for (int k = 0; k < 16; ++k) {
        int i = base + k * 256 + threadIdx.x;
        if (i < tot) {
            if (i < nx) atomicAdd(&h[xr[i] >> RBB_BITS], 1);
            else        atomicAdd(&h[NBMAX + (ar[i - nx] >> RBB_BITS)], 1);
        }
    }
    __syncthreads();
    for (int i = threadIdx.x; i < 2 * NBMAX; i += 256) {
        int c = h[i];
        if (c) {
            if (i < NBMAX) atomicAdd(&cx[i], c);
            else           atomicAdd(&ca[i - NBMAX], c);
        }
    }
}

// ---- exclusive scan of nb bin counts (mid path only, carry loop) ----
__global__ __launch_bounds__(1024) void scan_nb(const int* __restrict__ cx, const int* __restrict__ ca,
                                                int* __restrict__ bx, int* __restrict__ ba,
                                                int* __restrict__ curx, int* __restrict__ cura, int nb) {
    const int* c = blockIdx.x ? ca : cx;
    int* bs  = blockIdx.x ? ba : bx;
    int* cur = blockIdx.x ? cura : curx;
    __shared__ int wsum[16];
    __shared__ int woff[16];
    __shared__ int carry_s, chunk_tot;
    int tid = threadIdx.x, lane = tid & 63, wid = tid >> 6;
    if (tid == 0) carry_s = 0;
    __syncthreads();
    for (int base = 0; base < nb; base += 1024) {
        int i = base + tid;
        int v = (i < nb) ? c[i] : 0;
        int incl = wave_incl_scan(v, lane);
        if (lane == 63) wsum[wid] = incl;
        __syncthreads();
        if (wid == 0 && lane < 16) {
            int s = wsum[lane];
            int is = s;
            #pragma unroll
            for (int off = 1; off < 16; off <<= 1) {
                int up = __shfl_up(is, off, 64);
                if (lane >= off) is += up;
            }
            woff[lane] = is - s;
            if (lane == 15) chunk_tot = is;
        }
        __syncthreads();
        int excl = incl - v + woff[wid] + carry_s;
        if (i < nb) { bs[i] = excl; cur[i] = excl; }
        __syncthreads();
        if (tid == 0) carry_s += chunk_tot;
        __syncthreads();
    }
    if (tid == 0) bs[nb] = carry_s;
}

// ---- fused bin scatter with LDS sort + coalesced run writes (r8) ----
__global__ __launch_bounds__(512) void bucket_scatter2(const int* __restrict__ xr, const int* __restrict__ xc,
                                                       const float* __restrict__ xv, int nx,
                                                       const int* __restrict__ ar, const int* __restrict__ ac,
                                                       const float* __restrict__ av, int na,
                                                       int* __restrict__ curx, int* __restrict__ cura,
                                                       int2* __restrict__ stx, int2* __restrict__ sta,
                                                       int nb, int nblk_x, int capx, int capa) {
    const int* rows; const int* cols; const float* vals; int n;
    int* gcur; int2* stage; int base; int cap;
    if (blockIdx.x < nblk_x) {
        rows = xr; cols = xc; vals = xv; n = nx; gcur = curx; stage = stx;
        base = blockIdx.x * SCB; cap = capx;
    } else {
        rows = ar; cols = ac; vals = av; n = na; gcur = cura; stage = sta;
        base = (blockIdx.x - nblk_x) * SCB; cap = capa;
    }
    __shared__ int2 sp[SCB];
    __shared__ unsigned short bin16[SCB];
    __shared__ int cnt[NBIN];
    __shared__ int lbase[NBIN];
    __shared__ int gb[NBIN];
    __shared__ int tot_s;
    int tid = threadIdx.x, lane = tid & 63, wid = tid >> 6;
    for (int i = tid; i < NBIN; i += 512) cnt[i] = 0;
    __syncthreads();
    int rr[8]; int cc[8]; float vv[8];
    #pragma unroll
    for (int k = 0; k < 8; ++k) {
        int i = base + k * 512 + tid;
        rr[k] = -1;
        if (i < n) {
            rr[k] = __builtin_nontemporal_load(&rows[i]);
            cc[k] = __builtin_nontemporal_load(&cols[i]);
            vv[k] = __builtin_nontemporal_load(&vals[i]);
            atomicAdd(&cnt[rr[k] >> RBB_BITS], 1);
        }
    }
    __syncthreads();
    if (wid == 0) {
        int carry = 0;
        #pragma unroll
        for (int q = 0; q < NBIN / 64; ++q) {
            int k = (q << 6) + lane;
            int v = cnt[k];
            int incl = wave_incl_scan(v, lane) + carry;
            lbase[k] = incl - v;
            carry = __shfl(incl, 63, 64);
        }
        if (lane == 0) tot_s = carry;
    }
    __syncthreads();
    for (int b = tid; b < nb; b += 512) {
        int c = cnt[b];
        if (c) gb[b] = atomicAdd(&gcur[b], c);
        cnt[b] = lbase[b];
    }
    __syncthreads();
    #pragma unroll
    for (int k = 0; k < 8; ++k) {
        if (rr[k] >= 0) {
            int b = rr[k] >> RBB_BITS;
            int p = atomicAdd(&cnt[b], 1);
            sp[p] = make_int2(((rr[k] & (RBB - 1)) << 17) | cc[k], __float_as_int(vv[k]));
            bin16[p] = (unsigned short)b;
        }
    }
    __syncthreads();
    int tot = tot_s;
    for (int p = tid; p < tot; p += 512) {
        int2 e = sp[p];
        int b = bin16[p];
        int q = p - lbase[b];
        int r = gb[b];
        if (cap > 0) {
            int slot = r + q;
            if (slot < cap) stage[b * cap + slot] = e;
        } else {
            stage[r + q] = e;
        }
    }
}

// ======== consumer_xw_lds: persistent, whole Wh table in LDS ========
// 256 blocks (1/CU @ ~144 KB LDS). Stage Wh once via coalesced int4 loads,
// then loop bins: r8 sort passes (count/scan/rank) + accumulate where the
// per-edge Wh row read is a conflict-free ds_read (c*64+lane, 2 lanes/bank).

__global__ __launch_bounds__(CTH) void consumer_xw_lds(const int* __restrict__ gcnt,
                                                       const int2* __restrict__ stage,
                                                       const __half2* __restrict__ Wh,
                                                       __half2* __restrict__ xwh,
                                                       int N, int cap, int nbc, int whint4) {
    __shared__ int4 WhL4[WHL4MAX];       // 131072 B
    __shared__ int2 sp[CAPX];            // 12288 B
    __shared__ int hoff[NKEY + 1];
    __shared__ int curs[NKEY];
    int tid = threadIdx.x, lane = tid & 63, wid = tid >> 6;
    const int4* Wh4 = (const int4*)Wh;
    for (int i = tid; i < whint4; i += CTH) WhL4[i] = Wh4[i];
    const __half2* WhL = (const __half2*)WhL4;
    for (int b = blockIdx.x; b < nbc; b += gridDim.x) {
        int s = b * cap;
        int cnt = min(gcnt[b], cap);
        bool fast = (cnt <= CAPX);
        if (tid < NKEY) curs[tid] = 0;
        __syncthreads();   // covers Wh staging (1st iter) + prev-iter sp reads
        int2 pr[3];
        if (fast) {
            #pragma unroll
            for (int k = 0; k < 3; ++k) {
                int i = k * CTH + tid;
                if (i < cnt) {
                    pr[k] = nt_load_int2(&stage[s + i]);
                    atomicAdd(&curs[(pr[k].x >> 17) & (NKEY - 1)], 1);
                }
            }
        }
        __syncthreads();
        if (wid == 0) {
            int carry = 0;
            #pragma unroll
            for (int q = 0; q < 2; ++q) {
                int k = (q << 6) + lane;
                int v = curs[k];
                int incl = wave_incl_scan(v, lane) + carry;
                hoff[k] = incl - v;
                curs[k] = incl - v;
                carry = __shfl(incl, 63, 64);
            }
            if (lane == 0) hoff[NKEY] = carry;
        }
        __syncthreads();
        if (fast) {
            #pragma unroll
            for (int k = 0; k < 3; ++k) {
                int i = k * CTH + tid;
                if (i < cnt) {
                    int r = (pr[k].x >> 17) & (NKEY - 1);
                    sp[atomicAdd(&curs[r], 1)] = pr[k];
                }
            }
        }
        __syncthreads();
        int row0 = b << RBB_BITS;
        #pragma unroll 1
        for (int rr = 0; rr < NKEY / NW; ++rr) {
            int r = wid + rr * NW;
            int grow = row0 + r;
            if (grow >= N) continue;
            float ax = 0.f, ay = 0.f;
            if (fast) {
                int j = hoff[r], o1 = hoff[r + 1];
                for (; j + 3 < o1; j += 4) {
                    int2 c0 = sp[j], c1 = sp[j + 1], c2 = sp[j + 2], c3 = sp[j + 3];
                    float2 w0 = __half22float2(WhL[((c0.x & COLMASK) << 6) + lane]);
                    float2 w1 = __half22float2(WhL[((c1.x & COLMASK) << 6) + lane]);
                    float2 w2 = __half22float2(WhL[((c2.x & COLMASK) << 6) + lane]);
                    float2 w3 = __half22float2(WhL[((c3.x & COLMASK) << 6) + lane]);
                    float v0 = __int_as_float(c0.y), v1 = __int_as_float(c1.y);
                    float v2 = __int_as_float(c2.y), v3 = __int_as_float(c3.y);
                    ax += v0 * w0.x + v1 * w1.x + v2 * w2.x + v3 * w3.x;
                    ay += v0 * w0.y + v1 * w1.y + v2 * w2.y + v3 * w3.y;
                }
                for (; j < o1; ++j) {
                    int2 c0 = sp[j];
                    float2 w0 = __half22float2(WhL[((c0.x & COLMASK) << 6) + lane]);
                    float v0 = __int_as_float(c0.y);
                    ax += v0 * w0.x; ay += v0 * w0.y;
                }
            } else {
                for (int j = 0; j < cnt; ++j) {
                    int2 c0 = stage[s + j];
                    if (((c0.x >> 17) & (NKEY - 1)) == r) {
                        float2 w0 = __half22float2(WhL[((c0.x & COLMASK) << 6) + lane]);
                        float v0 = __int_as_float(c0.y);
                        ax += v0 * w0.x; ay += v0 * w0.y;
                    }
                }
            }
            xwh[((size_t)grow << 6) + lane] = __float22half2_rn(make_float2(ax, ay));
        }
        __syncthreads();   // all waves done with sp/hoff before next bin
    }
}

// ---- r8 consumer_xw (global Wh) — mid path / D_IN>512 fallback ----
__global__ __launch_bounds__(CTH) void consumer_xw(const int* __restrict__ bx, const int* __restrict__ gcnt,
                                                   const int2* __restrict__ stage,
                                                   const __half2* __restrict__ Wh, __half2* __restrict__ xwh,
                                                   int N, int cap) {
    __shared__ int2 sp[CAPX];
    __shared__ int hoff[NKEY + 1];
    __shared__ int curs[NKEY];
    int b = blockIdx.x;
    int s, cnt;
    if (cap > 0) { s = b * cap; cnt = min(gcnt[b], cap); }
    else         { s = bx[b]; cnt = bx[b + 1] - s; }
    int tid = threadIdx.x, lane = tid & 63, wid = tid >> 6;
    bool fast = (cnt <= CAPX);
    if (tid < NKEY) curs[tid] = 0;
    __syncthreads();
    int2 pr[3];
    if (fast) {
        #pragma unroll
        for (int k = 0; k < 3; ++k) {
            int i = k * CTH + tid;
            if (i < cnt) {
                pr[k] = nt_load_int2(&stage[s + i]);
                atomicAdd(&curs[(pr[k].x >> 17) & (NKEY - 1)], 1);
            }
        }
    }
    __syncthreads();
    if (wid == 0) {
        int carry = 0;
        #pragma unroll
        for (int q = 0; q < 2; ++q) {
            int k = (q << 6) + lane;
            int v = curs[k];
            int incl = wave_incl_scan(v, lane) + carry;
            hoff[k] = incl - v;
            curs[k] = incl - v;
            carry = __shfl(incl, 63, 64);
        }
        if (lane == 0) hoff[NKEY] = carry;
    }
    __syncthreads();
    if (fast) {
        #pragma unroll
        for (int k = 0; k < 3; ++k) {
            int i = k * CTH + tid;
            if (i < cnt) {
                int r = (pr[k].x >> 17) & (NKEY - 1);
                sp[atomicAdd(&curs[r], 1)] = pr[k];
            }
        }
    }
    __syncthreads();
    int row0 = b << RBB_BITS;
    #pragma unroll 1
    for (int rr = 0; rr < NKEY / NW; ++rr) {
        int r = wid + rr * NW;
        int grow = row0 + r;
        if (grow >= N) continue;
        float ax = 0.f, ay = 0.f;
        if (fast) {
            int j = hoff[r], o1 = hoff[r + 1];
            for (; j + 3 < o1; j += 4) {
                int2 c0 = sp[j], c1 = sp[j + 1], c2 = sp[j + 2], c3 = sp[j + 3];
                float2 w0 = __half22float2(Wh[((size_t)(c0.x & COLMASK) << 6) + lane]);
                float2 w1 = __half22float2(Wh[((size_t)(c1.x & COLMASK) << 6) + lane]);
                float2 w2 = __half22float2(Wh[((size_t)(c2.x & COLMASK) << 6) + lane]);
                float2 w3 = __half22float2(Wh[((size_t)(c3.x & COLMASK) << 6) + lane]);
                float v0 = __int_as_float(c0.y), v1 = __int_as_float(c1.y);
                float v2 = __int_as_float(c2.y), v3 = __int_as_float(c3.y);
                ax += v0 * w0.x + v1 * w1.x + v2 * w2.x + v3 * w3.x;
                ay += v0 * w0.y + v1 * w1.y + v2 * w2.y + v3 * w3.y;
            }
            for (; j < o1; ++j) {
                int2 c0 = sp[j];
                float2 w0 = __half22float2(Wh[((size_t)(c0.x & COLMASK) << 6) + lane]);
                float v0 = __int_as_float(c0.y);
                ax += v0 * w0.x; ay += v0 * w0.y;
            }
        } else {
            for (int j = 0; j < cnt; ++j) {
                int2 c0 = stage[s + j];
                if (((c0.x >> 17) & (NKEY - 1)) == r) {
                    float2 w0 = __half22float2(Wh[((size_t)(c0.x & COLMASK) << 6) + lane]);
                    float v0 = __int_as_float(c0.y);
                    ax += v0 * w0.x; ay += v0 * w0.y;
                }
            }
        }
        xwh[((size_t)grow << 6) + lane] = __float22half2_rn(make_float2(ax, ay));
    }
}

// ======== consumer_adj (round-8 structure, FROZEN) ========

__global__ __launch_bounds__(CTH) void consumer_adj(const int* __restrict__ ba, const int* __restrict__ gcnt,
                                                    const int2* __restrict__ stage,
                                                    const __half2* __restrict__ xwh, float* __restrict__ out,
                                                    int N, int cap) {
    __shared__ int2 sp[CAPA];
    __shared__ int hoff[NKEY + 1];
    __shared__ int curs[NKEY];
    int b = blockIdx.x;
    int s, cnt;
    if (cap > 0) { s = b * cap; cnt = min(gcnt[b], cap); }
    else         { s = ba[b]; cnt = ba[b + 1] - s; }
    int tid = threadIdx.x, lane = tid & 63, wid = tid >> 6;
    bool fast = (cnt <= CAPA);
    if (tid < NKEY) curs[tid] = 0;
    __syncthreads();
    int2 pr[6];
    if (fast) {
        #pragma unroll
        for (int k = 0; k < 6; ++k) {
            int i = k * CTH + tid;
            if (i < cnt) {
                pr[k] = nt_load_int2(&stage[s + i]);
                atomicAdd(&curs[(pr[k].x >> 17) & (NKEY - 1)], 1);
            }
        }
    }
    __syncthreads();
    if (wid == 0) {
        int carry = 0;
        #pragma unroll
        for (int q = 0; q < 2; ++q) {
            int k = (q << 6) + lane;
            int v = curs[k];
            int incl = wave_incl_scan(v, lane) + carry;
            hoff[k] = incl - v;
            curs[k] = incl - v;
            carry = __shfl(incl, 63, 64);
        }
        if (lane == 0) hoff[NKEY] = carry;
    }
    __syncthreads();
    if (fast) {
        #pragma unroll
        for (int k = 0; k < 6; ++k) {
            int i = k * CTH + tid;
            if (i < cnt) {
                int r = (pr[k].x >> 17) & (NKEY - 1);
                sp[atomicAdd(&curs[r], 1)] = pr[k];
            }
        }
    }
    __syncthreads();
    int row0 = b << RBB_BITS;
    #pragma unroll 1
    for (int rr = 0; rr < NKEY / NW; ++rr) {
        int r = wid + rr * NW;
        int grow = row0 + r;
        if (grow >= N) continue;
        float ax = 0.f, ay = 0.f;
        if (fast) {
            int j = hoff[r], o1 = hoff[r + 1];
            for (; j + 3 < o1; j += 4) {
                int2 c0 = sp[j], c1 = sp[j + 1], c2 = sp[j + 2], c3 = sp[j + 3];
                float2 h0 = __half22float2(xwh[((size_t)(c0.x & COLMASK) << 6) + lane]);
                float2 h1 = __half22float2(xwh[((size_t)(c1.x & COLMASK) << 6) + lane]);
                float2 h2 = __half22float2(xwh[((size_t)(c2.x & COLMASK) << 6) + lane]);
                float2 h3 = __half22float2(xwh[((size_t)(c3.x & COLMASK) << 6) + lane]);
                float v0 = __int_as_float(c0.y), v1 = __int_as_float(c1.y);
                float v2 = __int_as_float(c2.y), v3 = __int_as_float(c3.y);
                ax += v0 * h0.x + v1 * h1.x + v2 * h2.x + v3 * h3.x;
                ay += v0 * h0.y + v1 * h1.y + v2 * h2.y + v3 * h3.y;
            }
            for (; j < o1; ++j) {
                int2 c0 = sp[j];
                float2 h0 = __half22float2(xwh[((size_t)(c0.x & COLMASK) << 6) + lane]);
                float v0 = __int_as_float(c0.y);
                ax += v0 * h0.x; ay += v0 * h0.y;
            }
        } else {
            for (int j = 0; j < cnt; ++j) {
                int2 c0 = stage[s + j];
                if (((c0.x >> 17) & (NKEY - 1)) == r) {
                    float2 h0 = __half22float2(xwh[((size_t)(c0.x & COLMASK) << 6) + lane]);
                    float v0 = __int_as_float(c0.y);
                    ax += v0 * h0.x; ay += v0 * h0.y;
                }
            }
        }
        nt_store_float2(&((float2*)(out + (size_t)grow * DOUT))[lane],
                        make_float2(fmaxf(ax, 0.f), fmaxf(ay, 0.f)));
    }
}

// ---- last-resort fallback (atomic scatter) ----
__global__ void spmm_xw_atomic(const float* __restrict__ x_vals, const int* __restrict__ x_rows,
                               const int* __restrict__ x_cols, const float* __restrict__ W,
                               float* __restrict__ xw, int nnz) {
    long long t = (long long)blockIdx.x * blockDim.x + threadIdx.x;
    int i = (int)(t >> 7), d = (int)(t & 127);
    if (i >= nnz) return;
    atomicAdd(&xw[(long long)x_rows[i] * DOUT + d], x_vals[i] * W[(long long)x_cols[i] * DOUT + d]);
}
__global__ void spmm_adj_atomic(const float* __restrict__ adj_vals, const int* __restrict__ adj_rows,
                                const int* __restrict__ adj_cols, const float* __restrict__ xw,
                                float* __restrict__ out, int n_e) {
    long long t = (long long)blockIdx.x * blockDim.x + threadIdx.x;
    int e = (int)(t >> 7), d = (int)(t & 127);
    if (e >= n_e) return;
    atomicAdd(&out[(long long)adj_rows[e] * DOUT + d], adj_vals[e] * xw[(long long)adj_cols[e] * DOUT + d]);
}
__global__ void relu_kernel(float4* __restrict__ out, int n4) {
    int i = blockIdx.x * blockDim.x + threadIdx.x;
    if (i >= n4) return;
    float4 v = out[i];
    v.x = fmaxf(v.x, 0.f); v.y = fmaxf(v.y, 0.f);
    v.z = fmaxf(v.z, 0.f); v.w = fmaxf(v.w, 0.f);
    out[i] = v;
}

extern "C" void kernel_launch(void* const* d_in, const int* in_sizes, int n_in,
                              void* d_out, int out_size, void* d_ws, size_t ws_size,
                              hipStream_t stream) {
    const float* x_vals   = (const float*)d_in[0];
    const int*   x_rows   = (const int*)d_in[1];
    const int*   x_cols   = (const int*)d_in[2];
    const float* adj_vals = (const float*)d_in[3];
    const int*   adj_rows = (const int*)d_in[4];
    const int*   adj_cols = (const int*)d_in[5];
    const float* W        = (const float*)d_in[6];
    float* out = (float*)d_out;

    const int nnz_x = in_sizes[0];
    const int n_e   = in_sizes[3];
    const int N     = out_size / DOUT;
    const int D_IN  = in_sizes[6] / DOUT;
    const int nbc   = (N + RBB - 1) / RBB;

    // Workspace layout (common head)
    char* ws = (char*)d_ws;
    size_t off = 0;
    size_t xw_off   = off; off = align_up(off + (size_t)N * DOUT * sizeof(__half), 128);
    size_t wh_off   = off; off = align_up(off + (size_t)D_IN * 64 * sizeof(__half2), 128);
    size_t cx_off   = off; off += (size_t)NBMAX * sizeof(int);    // cx | ca adjacent
    size_t ca_off   = off; off = align_up(off + (size_t)NBMAX * sizeof(int), 128);
    size_t bx_off   = off; off = align_up(off + (size_t)(NBMAX + 1) * sizeof(int), 128);
    size_t baoff    = off; off = align_up(off + (size_t)(NBMAX + 1) * sizeof(int), 128);
    size_t head = off;
    // capped-stage layout
    size_t sxc_off = head;
    size_t sac_off = align_up(sxc_off + (size_t)nbc * CAPX * sizeof(int2), 128);
    size_t needed_cap = align_up(sac_off + (size_t)nbc * CAPA * sizeof(int2), 128);
    // scan-stage layout
    size_t sxm_off = head;
    size_t sam_off = align_up(sxm_off + (size_t)nnz_x * sizeof(int2), 128);
    size_t needed_mid = align_up(sam_off + (size_t)n_e * sizeof(int2), 128);

    bool ok_dims = (nbc <= NBIN) && (N <= (COLMASK + 1));
    const int ncnt = 2 * NBMAX;
    const int whtot = D_IN * 64;
    const int prep_n = (ncnt > whtot ? ncnt : whtot);

    if (ok_dims && ws_size >= needed_cap) {
        // ---------- capped fast path: prep -> scatter(x+a) -> xw_lds -> adj ----------
        __half2* xwh  = (__half2*)(ws + xw_off);
        __half2* Wh   = (__half2*)(ws + wh_off);
        int*  cx      = (int*)(ws + cx_off);
        int*  ca      = (int*)(ws + ca_off);
        int2* stage_x = (int2*)(ws + sxc_off);
        int2* stage_a = (int2*)(ws + sac_off);

        prep_kernel<<<(prep_n + 255) / 256, 256, 0, stream>>>(cx, ncnt, W, Wh, whtot);

        int nblk_x = (nnz_x + SCB - 1) / SCB;
        int nblk_a = (n_e + SCB - 1) / SCB;
        bucket_scatter2<<<nblk_x + nblk_a, 512, 0, stream>>>(x_rows, x_cols, x_vals, nnz_x,
                                                             adj_rows, adj_cols, adj_vals, n_e,
                                                             cx, ca, stage_x, stage_a,
                                                             nbc, nblk_x, CAPX, CAPA);
        if (D_IN <= 512) {
            int gxw = (nbc < 256) ? nbc : 256;
            consumer_xw_lds<<<gxw, CTH, 0, stream>>>(cx, stage_x, Wh, xwh, N, CAPX, nbc, D_IN * 16);
        } else {
            consumer_xw<<<nbc, CTH, 0, stream>>>(nullptr, cx, stage_x, Wh, xwh, N, CAPX);
        }
        consumer_adj<<<nbc, CTH, 0, stream>>>(nullptr, ca, stage_a, xwh, out, N, CAPA);
    } else if (ok_dims && ws_size >= needed_mid) {
        // ---------- mid path: hist + scan + packed stages (r8) ----------
        __half2* xwh  = (__half2*)(ws + xw_off);
        __half2* Wh   = (__half2*)(ws + wh_off);
        int*  cx      = (int*)(ws + cx_off);
        int*  ca      = (int*)(ws + ca_off);
        int*  bx      = (int*)(ws + bx_off);
        int*  ba      = (int*)(ws + baoff);
        int2* stage_x = (int2*)(ws + sxm_off);
        int2* stage_a = (int2*)(ws + sam_off);

        prep_kernel<<<(prep_n + 255) / 256, 256, 0, stream>>>(cx, ncnt, W, Wh, whtot);

        int tot = nnz_x + n_e;
        hist_coarse<<<(tot + 4095) / 4096, 256, 0, stream>>>(x_rows, nnz_x, adj_rows, n_e, cx, ca);
        scan_nb<<<2, 1024, 0, stream>>>(cx, ca, bx, ba, cx, ca, nbc);   // cursors reuse cx/ca

        int nblk_x = (nnz_x + SCB - 1) / SCB;
        int nblk_a = (n_e + SCB - 1) / SCB;
        bucket_scatter2<<<nblk_x + nblk_a, 512, 0, stream>>>(x_rows, x_cols, x_vals, nnz_x,
                                                             adj_rows, adj_cols, adj_vals, n_e,
                                                             cx, ca, stage_x, stage_a,
                                                             nbc, nblk_x, 0, 0);
        consumer_xw<<<nbc, CTH, 0, stream>>>(bx, nullptr, stage_x, Wh, xwh, N, 0);
        consumer_adj<<<nbc, CTH, 0, stream>>>(ba, nullptr, stage_a, xwh, out, N, 0);
    } else {
        // ---------- last-resort atomic path ----------
        float* xw = (float*)ws;
        hipMemsetAsync(xw, 0, (size_t)out_size * sizeof(float), stream);
        hipMemsetAsync(out, 0, (size_t)out_size * sizeof(float), stream);
        long long t1 = (long long)nnz_x * DOUT;
        spmm_xw_atomic<<<(int)((t1 + 255) / 256), 256, 0, stream>>>(x_vals, x_rows, x_cols, W, xw, nnz_x);
        long long t2 = (long long)n_e * DOUT;
        spmm_adj_atomic<<<(int)((t2 + 255) / 256), 256, 0, stream>>>(adj_vals, adj_rows, adj_cols, xw, out, n_e);
        relu_kernel<<<(out_size / 4 + 255) / 256, 256, 0, stream>>>((float4*)out, out_size / 4);
    }
}

// Round 12
// 201.953 us; speedup vs baseline: 1.0845x; 1.0845x over previous
//
#include <hip/hip_runtime.h>
#include <hip/hip_fp16.h>

// GraphConvolutionSparse forward. Coarse 128-row-bin sort + consumers that
// fine-sort each bin into LDS (128-key count/scan/rank) and register-
// accumulate rows (half2-per-lane gathers, unroll 4).
//
// Round-23: REVERT to round-8 exact (201.3 us, session best). Rounds 9-11
// each tested a theory of the ~135 us non-adj budget and regressed:
// r9 float4-xw (206, not issue-bound), r10 scatter||xw overlap (213,
// split-launch + LDS-occupancy cost), r11 Wh-in-LDS xw (219, 1 block/CU
// starved the stage/write streams). consumer_adj is at a delivered-BW
// ceiling: 410 MB logical gather / 65.5 us = 6.26 TB/s ~= the 6.29 TB/s
// achievable ceiling (9 confirmations; insensitive to occupancy 44-63%,
// orderings, cache hints, LDS accumulators). Scatter has its coalesced-
// store win (r8, WRITE-amp 4.4->~1.3); xw rejected vectorize/LDS/overlap.
// This decomposition is at its practical floor.
// LDS atomics are INT only (native ds_add) — never float (round-7 lesson).

#define DOUT 128
#define RBB 128           // rows per bin
#define RBB_BITS 7
#define NKEY 128          // consumer fine-sort keys = row-in-bin
#define NBIN 1024         // max bins (N <= 131072 / 128)
#define NBMAX 4096        // mid-path hist table size (legacy, >= NBIN)
#define COLMASK 131071    // low 17 bits
#define CTH 512           // consumer threads (8 waves)
#define NW 8              // waves per consumer block
#define CAPX 1536         // stage slots per bin, X (mean 1023, +16 sigma)
#define CAPA 3072         // stage slots per bin, A (mean 2046, +22 sigma)
#define SCB 4096          // scatter elements per block (8/thread)

static inline size_t align_up(size_t x, size_t a) { return (x + a - 1) & ~(a - 1); }

__device__ inline int2 nt_load_int2(const int2* p) {
    long long v = __builtin_nontemporal_load((const long long*)p);
    int2 r; r.x = (int)(unsigned int)(v & 0xffffffffLL); r.y = (int)(v >> 32);
    return r;
}
__device__ inline void nt_store_float2(float2* p, float2 v) {
    union { float2 f; long long l; } u; u.f = v;
    __builtin_nontemporal_store(u.l, (long long*)p);
}

__device__ inline int wave_incl_scan(int v, int lane) {
    #pragma unroll
    for (int off = 1; off < 64; off <<= 1) {
        int up = __shfl_up(v, off, 64);
        if (lane >= off) v += up;
    }
    return v;
}

// ---- prep: zero bin counters + build Wh pair table ----
// Wh[c*64+l] = half2(W[c][2l], W[c][2l+1])  (row = 64 half2 = 256 B)
__global__ __launch_bounds__(256) void prep_kernel(int* __restrict__ cnts, int ncnt,
                                                   const float* __restrict__ W,
                                                   __half2* __restrict__ Wh, int whtot) {
    int i = blockIdx.x * 256 + threadIdx.x;
    if (i < ncnt) cnts[i] = 0;
    if (i < whtot) {
        int c = i >> 6, l = i & 63;
        Wh[i] = __floats2half2_rn(W[(c << 7) + 2 * l], W[(c << 7) + 2 * l + 1]);
    }
}

// ---- coarse histogram (mid path only) ----
__global__ __launch_bounds__(256) void hist_coarse(const int* __restrict__ xr, int nx,
                                                   const int* __restrict__ ar, int na,
                                                   int* __restrict__ cx, int* __restrict__ ca) {
    __shared__ int h[2 * NBMAX];
    for (int i = threadIdx.x; i < 2 * NBMAX; i += 256) h[i] = 0;
    __syncthreads();
    int base = blockIdx.x * 4096;
    int tot = nx + na;
    #pragma unroll
    for (int k = 0; k < 16; ++k) {
        int i = base + k * 256 + threadIdx.x;
        if (i < tot) {
            if (i < nx) atomicAdd(&h[xr[i] >> RBB_BITS], 1);
            else        atomicAdd(&h[NBMAX + (ar[i - nx] >> RBB_BITS)], 1);
        }
    }
    __syncthreads();
    for (int i = threadIdx.x; i < 2 * NBMAX; i += 256) {
        int c = h[i];
        if (c) {
            if (i < NBMAX) atomicAdd(&cx[i], c);
            else           atomicAdd(&ca[i - NBMAX], c);
        }
    }
}

// ---- exclusive scan of nb bin counts (mid path only, carry loop) ----
__global__ __launch_bounds__(1024) void scan_nb(const int* __restrict__ cx, const int* __restrict__ ca,
                                                int* __restrict__ bx, int* __restrict__ ba,
                                                int* __restrict__ curx, int* __restrict__ cura, int nb) {
    const int* c = blockIdx.x ? ca : cx;
    int* bs  = blockIdx.x ? ba : bx;
    int* cur = blockIdx.x ? cura : curx;
    __shared__ int wsum[16];
    __shared__ int woff[16];
    __shared__ int carry_s, chunk_tot;
    int tid = threadIdx.x, lane = tid & 63, wid = tid >> 6;
    if (tid == 0) carry_s = 0;
    __syncthreads();
    for (int base = 0; base < nb; base += 1024) {
        int i = base + tid;
        int v = (i < nb) ? c[i] : 0;
        int incl = wave_incl_scan(v, lane);
        if (lane == 63) wsum[wid] = incl;
        __syncthreads();
        if (wid == 0 && lane < 16) {
            int s = wsum[lane];
            int is = s;
            #pragma unroll
            for (int off = 1; off < 16; off <<= 1) {
                int up = __shfl_up(is, off, 64);
                if (lane >= off) is += up;
            }
            woff[lane] = is - s;
            if (lane == 15) chunk_tot = is;
        }
        __syncthreads();
        int excl = incl - v + woff[wid] + carry_s;
        if (i < nb) { bs[i] = excl; cur[i] = excl; }
        __syncthreads();
        if (tid == 0) carry_s += chunk_tot;
        __syncthreads();
    }
    if (tid == 0) bs[nb] = carry_s;
}

// ---- fused bin scatter with LDS sort + coalesced run writes ----
// cap>0 => fixed-capacity mode (slots per bin), else absolute offsets in gcur.
__global__ __launch_bounds__(512) void bucket_scatter2(const int* __restrict__ xr, const int* __restrict__ xc,
                                                       const float* __restrict__ xv, int nx,
                                                       const int* __restrict__ ar, const int* __restrict__ ac,
                                                       const float* __restrict__ av, int na,
                                                       int* __restrict__ curx, int* __restrict__ cura,
                                                       int2* __restrict__ stx, int2* __restrict__ sta,
                                                       int nb, int nblk_x, int capx, int capa) {
    const int* rows; const int* cols; const float* vals; int n;
    int* gcur; int2* stage; int base; int cap;
    if (blockIdx.x < nblk_x) {
        rows = xr; cols = xc; vals = xv; n = nx; gcur = curx; stage = stx;
        base = blockIdx.x * SCB; cap = capx;
    } else {
        rows = ar; cols = ac; vals = av; n = na; gcur = cura; stage = sta;
        base = (blockIdx.x - nblk_x) * SCB; cap = capa;
    }
    __shared__ int2 sp[SCB];
    __shared__ unsigned short bin16[SCB];
    __shared__ int cnt[NBIN];      // counts -> rank cursors
    __shared__ int lbase[NBIN];    // local exclusive scan
    __shared__ int gb[NBIN];       // per-bin global reservation
    __shared__ int tot_s;
    int tid = threadIdx.x, lane = tid & 63, wid = tid >> 6;
    for (int i = tid; i < NBIN; i += 512) cnt[i] = 0;
    __syncthreads();
    int rr[8]; int cc[8]; float vv[8];
    #pragma unroll
    for (int k = 0; k < 8; ++k) {
        int i = base + k * 512 + tid;
        rr[k] = -1;
        if (i < n) {
            rr[k] = __builtin_nontemporal_load(&rows[i]);
            cc[k] = __builtin_nontemporal_load(&cols[i]);
            vv[k] = __builtin_nontemporal_load(&vals[i]);
            atomicAdd(&cnt[rr[k] >> RBB_BITS], 1);
        }
    }
    __syncthreads();
    // local exclusive scan over NBIN by wave 0 (16 chunks of 64, carry chain)
    if (wid == 0) {
        int carry = 0;
        #pragma unroll
        for (int q = 0; q < NBIN / 64; ++q) {
            int k = (q << 6) + lane;
            int v = cnt[k];
            int incl = wave_incl_scan(v, lane) + carry;
            lbase[k] = incl - v;
            carry = __shfl(incl, 63, 64);
        }
        if (lane == 0) tot_s = carry;
    }
    __syncthreads();
    // per-bin global reservation; convert cnt to rank cursor
    for (int b = tid; b < nb; b += 512) {
        int c = cnt[b];
        if (c) gb[b] = atomicAdd(&gcur[b], c);
        cnt[b] = lbase[b];
    }
    __syncthreads();
    // rank pass: sort payloads into sp[], remember bin
    #pragma unroll
    for (int k = 0; k < 8; ++k) {
        if (rr[k] >= 0) {
            int b = rr[k] >> RBB_BITS;
            int p = atomicAdd(&cnt[b], 1);
            sp[p] = make_int2(((rr[k] & (RBB - 1)) << 17) | cc[k], __float_as_int(vv[k]));
            bin16[p] = (unsigned short)b;
        }
    }
    __syncthreads();
    // linear write: consecutive p -> consecutive global addrs within each run
    int tot = tot_s;
    for (int p = tid; p < tot; p += 512) {
        int2 e = sp[p];
        int b = bin16[p];
        int q = p - lbase[b];
        int r = gb[b];
        if (cap > 0) {
            int slot = r + q;
            if (slot < cap) stage[b * cap + slot] = e;
        } else {
            stage[r + q] = e;
        }
    }
}

// ======== consumers: whole 128-row bin per block (512 thr, 8 waves) ========
// nt-load bin into registers -> 128-key LDS int-atomic count -> 2-pass wave
// scan -> rank pass sorts payloads into sp[] -> wave-per-row register
// accumulate (16 rows/wave, half2/lane gathers, unroll 4 — r3-proven body).

__global__ __launch_bounds__(CTH) void consumer_xw(const int* __restrict__ bx, const int* __restrict__ gcnt,
                                                   const int2* __restrict__ stage,
                                                   const __half2* __restrict__ Wh, __half2* __restrict__ xwh,
                                                   int N, int cap) {
    __shared__ int2 sp[CAPX];
    __shared__ int hoff[NKEY + 1];
    __shared__ int curs[NKEY];
    int b = blockIdx.x;
    int s, cnt;
    if (cap > 0) { s = b * cap; cnt = min(gcnt[b], cap); }
    else         { s = bx[b]; cnt = bx[b + 1] - s; }
    int tid = threadIdx.x, lane = tid & 63, wid = tid >> 6;
    bool fast = (cnt <= CAPX);
    if (tid < NKEY) curs[tid] = 0;
    __syncthreads();
    int2 pr[3];
    if (fast) {
        #pragma unroll
        for (int k = 0; k < 3; ++k) {
            int i = k * CTH + tid;
            if (i < cnt) {
                pr[k] = nt_load_int2(&stage[s + i]);
                atomicAdd(&curs[(pr[k].x >> 17) & (NKEY - 1)], 1);
            }
        }
    }
    __syncthreads();
    if (wid == 0) {
        int carry = 0;
        #pragma unroll
        for (int q = 0; q < 2; ++q) {
            int k = (q << 6) + lane;
            int v = curs[k];
            int incl = wave_incl_scan(v, lane) + carry;
            hoff[k] = incl - v;
            curs[k] = incl - v;
            carry = __shfl(incl, 63, 64);
        }
        if (lane == 0) hoff[NKEY] = carry;
    }
    __syncthreads();
    if (fast) {
        #pragma unroll
        for (int k = 0; k < 3; ++k) {
            int i = k * CTH + tid;
            if (i < cnt) {
                int r = (pr[k].x >> 17) & (NKEY - 1);
                sp[atomicAdd(&curs[r], 1)] = pr[k];
            }
        }
    }
    __syncthreads();
    int row0 = b << RBB_BITS;
    #pragma unroll 1
    for (int rr = 0; rr < NKEY / NW; ++rr) {
        int r = wid + rr * NW;
        int grow = row0 + r;
        if (grow >= N) continue;
        float ax = 0.f, ay = 0.f;
        if (fast) {
            int j = hoff[r], o1 = hoff[r + 1];
            for (; j + 3 < o1; j += 4) {
                int2 c0 = sp[j], c1 = sp[j + 1], c2 = sp[j + 2], c3 = sp[j + 3];
                float2 w0 = __half22float2(Wh[((size_t)(c0.x & COLMASK) << 6) + lane]);
                float2 w1 = __half22float2(Wh[((size_t)(c1.x & COLMASK) << 6) + lane]);
                float2 w2 = __half22float2(Wh[((size_t)(c2.x & COLMASK) << 6) + lane]);
                float2 w3 = __half22float2(Wh[((size_t)(c3.x & COLMASK) << 6) + lane]);
                float v0 = __int_as_float(c0.y), v1 = __int_as_float(c1.y);
                float v2 = __int_as_float(c2.y), v3 = __int_as_float(c3.y);
                ax += v0 * w0.x + v1 * w1.x + v2 * w2.x + v3 * w3.x;
                ay += v0 * w0.y + v1 * w1.y + v2 * w2.y + v3 * w3.y;
            }
            for (; j < o1; ++j) {
                int2 c0 = sp[j];
                float2 w0 = __half22float2(Wh[((size_t)(c0.x & COLMASK) << 6) + lane]);
                float v0 = __int_as_float(c0.y);
                ax += v0 * w0.x; ay += v0 * w0.y;
            }
        } else {
            for (int j = 0; j < cnt; ++j) {
                int2 c0 = stage[s + j];
                if (((c0.x >> 17) & (NKEY - 1)) == r) {
                    float2 w0 = __half22float2(Wh[((size_t)(c0.x & COLMASK) << 6) + lane]);
                    float v0 = __int_as_float(c0.y);
                    ax += v0 * w0.x; ay += v0 * w0.y;
                }
            }
        }
        xwh[((size_t)grow << 6) + lane] = __float22half2_rn(make_float2(ax, ay));
    }
}

__global__ __launch_bounds__(CTH) void consumer_adj(const int* __restrict__ ba, const int* __restrict__ gcnt,
                                                    const int2* __restrict__ stage,
                                                    const __half2* __restrict__ xwh, float* __restrict__ out,
                                                    int N, int cap) {
    __shared__ int2 sp[CAPA];
    __shared__ int hoff[NKEY + 1];
    __shared__ int curs[NKEY];
    int b = blockIdx.x;
    int s, cnt;
    if (cap > 0) { s = b * cap; cnt = min(gcnt[b], cap); }
    else         { s = ba[b]; cnt = ba[b + 1] - s; }
    int tid = threadIdx.x, lane = tid & 63, wid = tid >> 6;
    bool fast = (cnt <= CAPA);
    if (tid < NKEY) curs[tid] = 0;
    __syncthreads();
    int2 pr[6];
    if (fast) {
        #pragma unroll
        for (int k = 0; k < 6; ++k) {
            int i = k * CTH + tid;
            if (i < cnt) {
                pr[k] = nt_load_int2(&stage[s + i]);
                atomicAdd(&curs[(pr[k].x >> 17) & (NKEY - 1)], 1);
            }
        }
    }
    __syncthreads();
    if (wid == 0) {
        int carry = 0;
        #pragma unroll
        for (int q = 0; q < 2; ++q) {
            int k = (q << 6) + lane;
            int v = curs[k];
            int incl = wave_incl_scan(v, lane) + carry;
            hoff[k] = incl - v;
            curs[k] = incl - v;
            carry = __shfl(incl, 63, 64);
        }
        if (lane == 0) hoff[NKEY] = carry;
    }
    __syncthreads();
    if (fast) {
        #pragma unroll
        for (int k = 0; k < 6; ++k) {
            int i = k * CTH + tid;
            if (i < cnt) {
                int r = (pr[k].x >> 17) & (NKEY - 1);
                sp[atomicAdd(&curs[r], 1)] = pr[k];
            }
        }
    }
    __syncthreads();
    int row0 = b << RBB_BITS;
    #pragma unroll 1
    for (int rr = 0; rr < NKEY / NW; ++rr) {
        int r = wid + rr * NW;
        int grow = row0 + r;
        if (grow >= N) continue;
        float ax = 0.f, ay = 0.f;
        if (fast) {
            int j = hoff[r], o1 = hoff[r + 1];
            for (; j + 3 < o1; j += 4) {
                int2 c0 = sp[j], c1 = sp[j + 1], c2 = sp[j + 2], c3 = sp[j + 3];
                float2 h0 = __half22float2(xwh[((size_t)(c0.x & COLMASK) << 6) + lane]);
                float2 h1 = __half22float2(xwh[((size_t)(c1.x & COLMASK) << 6) + lane]);
                float2 h2 = __half22float2(xwh[((size_t)(c2.x & COLMASK) << 6) + lane]);
                float2 h3 = __half22float2(xwh[((size_t)(c3.x & COLMASK) << 6) + lane]);
                float v0 = __int_as_float(c0.y), v1 = __int_as_float(c1.y);
                float v2 = __int_as_float(c2.y), v3 = __int_as_float(c3.y);
                ax += v0 * h0.x + v1 * h1.x + v2 * h2.x + v3 * h3.x;
                ay += v0 * h0.y + v1 * h1.y + v2 * h2.y + v3 * h3.y;
            }
            for (; j < o1; ++j) {
                int2 c0 = sp[j];
                float2 h0 = __half22float2(xwh[((size_t)(c0.x & COLMASK) << 6) + lane]);
                float v0 = __int_as_float(c0.y);
                ax += v0 * h0.x; ay += v0 * h0.y;
            }
        } else {
            for (int j = 0; j < cnt; ++j) {
                int2 c0 = stage[s + j];
                if (((c0.x >> 17) & (NKEY - 1)) == r) {
                    float2 h0 = __half22float2(xwh[((size_t)(c0.x & COLMASK) << 6) + lane]);
                    float v0 = __int_as_float(c0.y);
                    ax += v0 * h0.x; ay += v0 * h0.y;
                }
            }
        }
        nt_store_float2(&((float2*)(out + (size_t)grow * DOUT))[lane],
                        make_float2(fmaxf(ax, 0.f), fmaxf(ay, 0.f)));
    }
}

// ---- last-resort fallback (atomic scatter) ----
__global__ void spmm_xw_atomic(const float* __restrict__ x_vals, const int* __restrict__ x_rows,
                               const int* __restrict__ x_cols, const float* __restrict__ W,
                               float* __restrict__ xw, int nnz) {
    long long t = (long long)blockIdx.x * blockDim.x + threadIdx.x;
    int i = (int)(t >> 7), d = (int)(t & 127);
    if (i >= nnz) return;
    atomicAdd(&xw[(long long)x_rows[i] * DOUT + d], x_vals[i] * W[(long long)x_cols[i] * DOUT + d]);
}
__global__ void spmm_adj_atomic(const float* __restrict__ adj_vals, const int* __restrict__ adj_rows,
                                const int* __restrict__ adj_cols, const float* __restrict__ xw,
                                float* __restrict__ out, int n_e) {
    long long t = (long long)blockIdx.x * blockDim.x + threadIdx.x;
    int e = (int)(t >> 7), d = (int)(t & 127);
    if (e >= n_e) return;
    atomicAdd(&out[(long long)adj_rows[e] * DOUT + d], adj_vals[e] * xw[(long long)adj_cols[e] * DOUT + d]);
}
__global__ void relu_kernel(float4* __restrict__ out, int n4) {
    int i = blockIdx.x * blockDim.x + threadIdx.x;
    if (i >= n4) return;
    float4 v = out[i];
    v.x = fmaxf(v.x, 0.f); v.y = fmaxf(v.y, 0.f);
    v.z = fmaxf(v.z, 0.f); v.w = fmaxf(v.w, 0.f);
    out[i] = v;
}

extern "C" void kernel_launch(void* const* d_in, const int* in_sizes, int n_in,
                              void* d_out, int out_size, void* d_ws, size_t ws_size,
                              hipStream_t stream) {
    const float* x_vals   = (const float*)d_in[0];
    const int*   x_rows   = (const int*)d_in[1];
    const int*   x_cols   = (const int*)d_in[2];
    const float* adj_vals = (const float*)d_in[3];
    const int*   adj_rows = (const int*)d_in[4];
    const int*   adj_cols = (const int*)d_in[5];
    const float* W        = (const float*)d_in[6];
    float* out = (float*)d_out;

    const int nnz_x = in_sizes[0];
    const int n_e   = in_sizes[3];
    const int N     = out_size / DOUT;
    const int D_IN  = in_sizes[6] / DOUT;
    const int nbc   = (N + RBB - 1) / RBB;

    // Workspace layout (common head)
    char* ws = (char*)d_ws;
    size_t off = 0;
    size_t xw_off   = off; off = align_up(off + (size_t)N * DOUT * sizeof(__half), 128);
    size_t wh_off   = off; off = align_up(off + (size_t)D_IN * 64 * sizeof(__half2), 128);
    size_t cx_off   = off; off += (size_t)NBMAX * sizeof(int);    // cx | ca adjacent
    size_t ca_off   = off; off = align_up(off + (size_t)NBMAX * sizeof(int), 128);
    size_t bx_off   = off; off = align_up(off + (size_t)(NBMAX + 1) * sizeof(int), 128);
    size_t baoff    = off; off = align_up(off + (size_t)(NBMAX + 1) * sizeof(int), 128);
    size_t head = off;
    // capped-stage layout
    size_t sxc_off = head;
    size_t sac_off = align_up(sxc_off + (size_t)nbc * CAPX * sizeof(int2), 128);
    size_t needed_cap = align_up(sac_off + (size_t)nbc * CAPA * sizeof(int2), 128);
    // scan-stage layout
    size_t sxm_off = head;
    size_t sam_off = align_up(sxm_off + (size_t)nnz_x * sizeof(int2), 128);
    size_t needed_mid = align_up(sam_off + (size_t)n_e * sizeof(int2), 128);

    bool ok_dims = (nbc <= NBIN) && (N <= (COLMASK + 1));
    const int ncnt = 2 * NBMAX;
    const int whtot = D_IN * 64;
    const int prep_n = (ncnt > whtot ? ncnt : whtot);

    if (ok_dims && ws_size >= needed_cap) {
        // ---------- capped fast path: no hist, no scan ----------
        __half2* xwh  = (__half2*)(ws + xw_off);
        __half2* Wh   = (__half2*)(ws + wh_off);
        int*  cx      = (int*)(ws + cx_off);
        int*  ca      = (int*)(ws + ca_off);
        int2* stage_x = (int2*)(ws + sxc_off);
        int2* stage_a = (int2*)(ws + sac_off);

        prep_kernel<<<(prep_n + 255) / 256, 256, 0, stream>>>(cx, ncnt, W, Wh, whtot);

        int nblk_x = (nnz_x + SCB - 1) / SCB;
        int nblk_a = (n_e + SCB - 1) / SCB;
        bucket_scatter2<<<nblk_x + nblk_a, 512, 0, stream>>>(x_rows, x_cols, x_vals, nnz_x,
                                                             adj_rows, adj_cols, adj_vals, n_e,
                                                             cx, ca, stage_x, stage_a,
                                                             nbc, nblk_x, CAPX, CAPA);
        consumer_xw<<<nbc, CTH, 0, stream>>>(nullptr, cx, stage_x, Wh, xwh, N, CAPX);
        consumer_adj<<<nbc, CTH, 0, stream>>>(nullptr, ca, stage_a, xwh, out, N, CAPA);
    } else if (ok_dims && ws_size >= needed_mid) {
        // ---------- mid path: hist + scan + packed stages ----------
        __half2* xwh  = (__half2*)(ws + xw_off);
        __half2* Wh   = (__half2*)(ws + wh_off);
        int*  cx      = (int*)(ws + cx_off);
        int*  ca      = (int*)(ws + ca_off);
        int*  bx      = (int*)(ws + bx_off);
        int*  ba      = (int*)(ws + baoff);
        int2* stage_x = (int2*)(ws + sxm_off);
        int2* stage_a = (int2*)(ws + sam_off);

        prep_kernel<<<(prep_n + 255) / 256, 256, 0, stream>>>(cx, ncnt, W, Wh, whtot);

        int tot = nnz_x + n_e;
        hist_coarse<<<(tot + 4095) / 4096, 256, 0, stream>>>(x_rows, nnz_x, adj_rows, n_e, cx, ca);
        scan_nb<<<2, 1024, 0, stream>>>(cx, ca, bx, ba, cx, ca, nbc);   // cursors reuse cx/ca

        int nblk_x = (nnz_x + SCB - 1) / SCB;
        int nblk_a = (n_e + SCB - 1) / SCB;
        bucket_scatter2<<<nblk_x + nblk_a, 512, 0, stream>>>(x_rows, x_cols, x_vals, nnz_x,
                                                             adj_rows, adj_cols, adj_vals, n_e,
                                                             cx, ca, stage_x, stage_a,
                                                             nbc, nblk_x, 0, 0);
        consumer_xw<<<nbc, CTH, 0, stream>>>(bx, nullptr, stage_x, Wh, xwh, N, 0);
        consumer_adj<<<nbc, CTH, 0, stream>>>(ba, nullptr, stage_a, xwh, out, N, 0);
    } else {
        // ---------- last-resort atomic path ----------
        float* xw = (float*)ws;
        hipMemsetAsync(xw, 0, (size_t)out_size * sizeof(float), stream);
        hipMemsetAsync(out, 0, (size_t)out_size * sizeof(float), stream);
        long long t1 = (long long)nnz_x * DOUT;
        spmm_xw_atomic<<<(int)((t1 + 255) / 256), 256, 0, stream>>>(x_vals, x_rows, x_cols, W, xw, nnz_x);
        long long t2 = (long long)n_e * DOUT;
        spmm_adj_atomic<<<(int)((t2 + 255) / 256), 256, 0, stream>>>(adj_vals, adj_rows, adj_cols, xw, out, n_e);
        relu_kernel<<<(out_size / 4 + 255) / 256, 256, 0, stream>>>((float4*)out, out_size / 4);
    }
}